// Round 4
// baseline (167.850 us; speedup 1.0000x reference)
//
#include <hip/hip_runtime.h>

typedef unsigned short u16;
typedef unsigned int   u32;
typedef __bf16 bf16x2 __attribute__((ext_vector_type(2)));
typedef __bf16 bf16x8 __attribute__((ext_vector_type(8)));
typedef float  f32x4  __attribute__((ext_vector_type(4)));
typedef float  f32x16 __attribute__((ext_vector_type(16)));
typedef u32    u32x4  __attribute__((ext_vector_type(4)));

#define LOG2E 1.4426950408889634f

// fp32 -> bf16 round-to-nearest-even
__device__ __forceinline__ u16 f2bf(float f) {
  union { float f; u32 u; } v; v.f = f;
  u32 r = v.u + 0x7fffu + ((v.u >> 16) & 1u);
  return (u16)(r >> 16);
}

// pair-pack via __bf16 casts -> compiler can select v_cvt_pk_bf16_f32 (RNE)
__device__ __forceinline__ u32 pack2(float lo, float hi) {
  bf16x2 p = { (__bf16)lo, (__bf16)hi };
  return __builtin_bit_cast(u32, p);
}

#define GLOAD_LDS16(g, s) __builtin_amdgcn_global_load_lds( \
    (const __attribute__((address_space(1))) void*)(g),     \
    (__attribute__((address_space(3))) void*)(s), 16, 0, 0)

// ---------------- prep kernels ----------------

__global__ void k_convert(const float* __restrict__ in, u16* __restrict__ out) {
  int i = (blockIdx.x * 256 + threadIdx.x) * 8;
  float4 a = *(const float4*)(in + i);
  float4 b = *(const float4*)(in + i + 4);
  u16 o[8] = { f2bf(a.x), f2bf(a.y), f2bf(a.z), f2bf(a.w),
               f2bf(b.x), f2bf(b.y), f2bf(b.z), f2bf(b.w) };
  *(uint4*)(out + i) = *(const uint4*)o;
}

// W [1024][1024] f32 (k-major) -> WT [1024][1024] bf16 (n-major): WT[n][k] = W[k][n]
__global__ void k_transpose_w(const float* __restrict__ W, u16* __restrict__ WT) {
  __shared__ float tile[64][65];
  const int t = threadIdx.x;
  const int n0 = blockIdx.x * 64, k0 = blockIdx.y * 64;
  const int r = t >> 4, c4 = (t & 15) * 4;
  #pragma unroll
  for (int rr = 0; rr < 64; rr += 16) {
    float4 v = *(const float4*)(W + (size_t)(k0 + r + rr) * 1024 + n0 + c4);
    tile[r + rr][c4]     = v.x; tile[r + rr][c4 + 1] = v.y;
    tile[r + rr][c4 + 2] = v.z; tile[r + rr][c4 + 3] = v.w;
  }
  __syncthreads();
  #pragma unroll
  for (int rr = 0; rr < 64; rr += 16) {
    u16 o[4] = { f2bf(tile[c4][r + rr]),     f2bf(tile[c4 + 1][r + rr]),
                 f2bf(tile[c4 + 2][r + rr]), f2bf(tile[c4 + 3][r + rr]) };
    *(ushort4*)(WT + (size_t)(n0 + r + rr) * 1024 + k0 + c4) = *(const ushort4*)o;
  }
}

// V region of QKV (cols 2048..3071) -> VT[1024][4096] bf16: VT[d][tok] = V[tok][d]
__global__ void k_transpose_v(const u16* __restrict__ qkv, u16* __restrict__ vt) {
  __shared__ u16 tile[64][72];
  const int t = threadIdx.x;
  const int c0 = blockIdx.x * 64;   // d
  const int r0 = blockIdx.y * 64;   // token
  const int rr = t >> 3;            // 0..31
  const int cc = (t & 7) * 8;       // 0..56
  #pragma unroll
  for (int j = 0; j < 2; ++j) {
    int r = rr + j * 32;
    *(uint4*)&tile[r][cc] = *(const uint4*)(qkv + (size_t)(r0 + r) * 3072 + 2048 + c0 + cc);
  }
  __syncthreads();
  #pragma unroll
  for (int j = 0; j < 2; ++j) {
    int c = rr + j * 32;
    u16 o[8];
    #pragma unroll
    for (int k = 0; k < 8; ++k) o[k] = tile[cc + k][c];
    *(uint4*)(vt + (size_t)(c0 + c) * 4096 + r0 + cc) = *(const uint4*)o;
  }
}

// ---------------- GEMM: C[M][N] = A[M][K] * BT[N][K]^T ----------------

template<int OUTF32>
__global__ __launch_bounds__(256) void k_gemm_bt(
    const u16* __restrict__ A, const u16* __restrict__ BT,
    void* __restrict__ Cv, const float* __restrict__ bias,
    int M, int N, int K) {
  __shared__ u16 lA[2][128 * 32];
  __shared__ u16 lB[2][128 * 32];
  const int t = threadIdx.x;
  const int l = t & 63, w = t >> 6;
  const int bM = blockIdx.y * 128, bN = blockIdx.x * 128;
  const int wr = w >> 1, wc = w & 1;
  const int NT = K >> 5;

  f32x4 acc[4][4] = {};

  const int fA  = w * 512 + l * 8;
  const int r0  = fA >> 5;
  const int kc0 = fA & 31;

  auto stage = [&](int buf, int kt) {
    const u16* ga = A  + (size_t)(bM + r0) * K + kt * 32 + kc0;
    const u16* gb = BT + (size_t)(bN + r0) * K + kt * 32 + kc0;
    GLOAD_LDS16(ga, &lA[buf][w * 512]);
    GLOAD_LDS16(gb, &lB[buf][w * 512]);
    GLOAD_LDS16(ga + (size_t)64 * K, &lA[buf][2048 + w * 512]);
    GLOAD_LDS16(gb + (size_t)64 * K, &lB[buf][2048 + w * 512]);
  };

  stage(0, 0);
  __syncthreads();
  int buf = 0;
  for (int kt = 0; kt < NT; ++kt) {
    if (kt + 1 < NT) stage(buf ^ 1, kt + 1);
    bf16x8 af[4], bfr[4];
    #pragma unroll
    for (int m = 0; m < 4; ++m)
      af[m] = *(const bf16x8*)&lA[buf][(wr * 64 + m * 16 + (l & 15)) * 32 + (l >> 4) * 8];
    #pragma unroll
    for (int n = 0; n < 4; ++n)
      bfr[n] = *(const bf16x8*)&lB[buf][(wc * 64 + n * 16 + (l & 15)) * 32 + (l >> 4) * 8];
    #pragma unroll
    for (int m = 0; m < 4; ++m)
      #pragma unroll
      for (int n = 0; n < 4; ++n)
        acc[m][n] = __builtin_amdgcn_mfma_f32_16x16x32_bf16(af[m], bfr[n], acc[m][n], 0, 0, 0);
    __syncthreads();
    buf ^= 1;
  }

  #pragma unroll
  for (int m = 0; m < 4; ++m) {
    #pragma unroll
    for (int n = 0; n < 4; ++n) {
      const int row = bM + wr * 64 + m * 16 + (l >> 4) * 4;
      const int col = bN + wc * 64 + n * 16 + (l & 15);
      #pragma unroll
      for (int i = 0; i < 4; ++i) {
        if (OUTF32) ((float*)Cv)[(size_t)(row + i) * N + col] = acc[m][n][i] + bias[col];
        else        ((u16*)Cv)[(size_t)(row + i) * N + col]   = f2bf(acc[m][n][i]);
      }
    }
  }
}

// ---------------- flash attention (causal, no scale) ----------------
// 2048 blocks x 128 threads (2 waves). One (bh, qt) task per block; wave w
// handles k-tiles [t0,t1) with part1 (w=1) owning the diagonal. Partial
// (m, l, O) states merged via LDS. Long tasks dispatch first per XCD.
// S^T via swapped mfma(K,Q) 32x32x16; C/D: col=lane&31, row=(r&3)+8(r>>2)+4hi.

__global__ __launch_bounds__(128, 4) void k_attn(
    const u16* __restrict__ qkv, const u16* __restrict__ vtg, u16* __restrict__ ctx) {
  __shared__ float obuf[2048];   // partner O: [q(32)][d(64)]
  __shared__ float mbuf[32];     // partner m per q-row
  __shared__ float lbuf[64];     // partner lh per lane (half-partial)

  const int t = threadIdx.x;
  const int l = t & 63, w = t >> 6;        // w = part id 0/1
  const int hi = l >> 5, ln = l & 31;
  const int bidx = blockIdx.x;
  const int x = bidx & 7, g = bidx >> 3;   // XCD slot, group
  const int bh = x * 4 + (g & 3);          // 4 heads per XCD slot (L2 residency)
  const int qt = 63 - (g >> 2);            // long tasks first
  const int bb = bh >> 4, h = bh & 15;
  const size_t tokbase = (size_t)bb * 2048;

  const int half = (qt + 1) >> 1;
  const int t0 = w ? half : 0;
  const int t1 = w ? (qt + 1) : half;
  const int nt = t1 - t0;

  // Q B-fragments (both waves load same q-tile)
  bf16x8 qf[4];
  {
    const u16* qq = qkv + (tokbase + qt * 32 + ln) * 3072 + h * 64 + hi * 8;
    #pragma unroll
    for (int ds = 0; ds < 4; ++ds) qf[ds] = *(const bf16x8*)(qq + ds * 16);
  }

  const u16* kp  = qkv + (tokbase + t0 * 32 + ln) * 3072 + 1024 + h * 64 + hi * 8;
  const u16* vp0 = vtg + (size_t)(h * 64 + ln) * 4096 + tokbase + t0 * 32 + hi * 8;
  const u16* vp1 = vp0 + (size_t)32 * 4096;

  f32x16 oa = {}, ob = {};
  float m = -__builtin_inff(), lh = 0.f;

  bf16x8 kA[4], kB[4];
  auto loadK = [&](bf16x8 (&kf)[4]) {
    #pragma unroll
    for (int ds = 0; ds < 4; ++ds) kf[ds] = *(const bf16x8*)(kp + ds * 16);
    kp += 32 * 3072;
  };

  auto process = [&](bf16x8 (&kf)[4], bool diag) {
    // S^T = K * Q^T
    f32x16 sc = {};
    #pragma unroll
    for (int ds = 0; ds < 4; ++ds)
      sc = __builtin_amdgcn_mfma_f32_32x32x16_bf16(kf[ds], qf[ds], sc, 0, 0, 0);

    if (diag) {
      #pragma unroll
      for (int r = 0; r < 16; ++r) {
        const int kloc = (r & 3) + 8 * (r >> 2) + 4 * hi;
        if (kloc > ln) sc[r] = -__builtin_inff();
      }
    }

    float pm = sc[0];
    #pragma unroll
    for (int r = 1; r < 16; ++r) pm = fmaxf(pm, sc[r]);
    pm = fmaxf(pm, __shfl_xor(pm, 32));

    if (!__all(pm <= m + 8.0f)) {   // defer-max (T13)
      const float mn  = fmaxf(m, pm);
      const float scl = exp2f((m - mn) * LOG2E);
      m = mn;
      lh *= scl;
      #pragma unroll
      for (int r = 0; r < 16; ++r) {
        const float sr = __shfl(scl, (r & 3) + 8 * (r >> 2) + 4 * hi);
        oa[r] *= sr; ob[r] *= sr;
      }
    }

    // V fragments (issued here: exp/pack below hides the L2 latency;
    // keeps peak VGPR under the (128,4) budget)
    bf16x8 v00 = *(const bf16x8*)(vp0);
    bf16x8 v01 = *(const bf16x8*)(vp0 + 16);
    bf16x8 v10 = *(const bf16x8*)(vp1);
    bf16x8 v11 = *(const bf16x8*)(vp1 + 16);
    vp0 += 32; vp1 += 32;

    float ph[16];
    #pragma unroll
    for (int r = 0; r < 16; ++r) ph[r] = exp2f((sc[r] - m) * LOG2E);
    float rs = 0.f;
    #pragma unroll
    for (int r = 0; r < 16; ++r) rs += ph[r];
    lh += rs;

    u32 c0 = pack2(ph[0],  ph[1]),  c1 = pack2(ph[2],  ph[3]);
    u32 c2 = pack2(ph[4],  ph[5]),  c3 = pack2(ph[6],  ph[7]);
    u32 c4 = pack2(ph[8],  ph[9]),  c5 = pack2(ph[10], ph[11]);
    u32 c6 = pack2(ph[12], ph[13]), c7 = pack2(ph[14], ph[15]);
    const u32 s0 = __shfl_xor(c0, 32), s1 = __shfl_xor(c1, 32);
    const u32 s2 = __shfl_xor(c2, 32), s3 = __shfl_xor(c3, 32);
    const u32 s4 = __shfl_xor(c4, 32), s5 = __shfl_xor(c5, 32);
    const u32 s6 = __shfl_xor(c6, 32), s7 = __shfl_xor(c7, 32);
    const bool h0 = (hi == 0);
    u32x4 wa0 = { h0 ? c0 : s2, h0 ? c1 : s3, h0 ? s0 : c2, h0 ? s1 : c3 };
    u32x4 wa1 = { h0 ? c4 : s6, h0 ? c5 : s7, h0 ? s4 : c6, h0 ? s5 : c7 };
    bf16x8 pa0 = __builtin_bit_cast(bf16x8, wa0);
    bf16x8 pa1 = __builtin_bit_cast(bf16x8, wa1);

    oa = __builtin_amdgcn_mfma_f32_32x32x16_bf16(pa0, v00, oa, 0, 0, 0);
    oa = __builtin_amdgcn_mfma_f32_32x32x16_bf16(pa1, v01, oa, 0, 0, 0);
    ob = __builtin_amdgcn_mfma_f32_32x32x16_bf16(pa0, v10, ob, 0, 0, 0);
    ob = __builtin_amdgcn_mfma_f32_32x32x16_bf16(pa1, v11, ob, 0, 0, 0);
  };

  if (nt > 0) {
    loadK(kA);
    for (int i = 0; i < nt; i += 2) {
      const bool more1 = (i + 1 < nt);
      if (more1) loadK(kB);
      process(kA, t0 + i == qt);
      if (more1) {
        if (i + 2 < nt) loadK(kA);
        process(kB, t0 + i + 1 == qt);
      }
    }
  }

  // ---- merge part1 into part0 via LDS, wave0 stores ----
  if (w == 1) {
    if (hi == 0) mbuf[ln] = m;
    lbuf[l] = lh;
    #pragma unroll
    for (int r = 0; r < 16; ++r) {
      const int rm = (r & 3) + 8 * (r >> 2) + 4 * hi;
      obuf[rm * 64 + ln]      = oa[r];
      obuf[rm * 64 + 32 + ln] = ob[r];
    }
  }
  __syncthreads();
  if (w == 0) {
    const float mB = mbuf[ln];
    const float lB = lbuf[l];
    const float ms = fmaxf(m, mB);
    const float sA = exp2f((m - ms) * LOG2E);   // exp2(-inf)=0 handles empty part0
    const float sB = exp2f((mB - ms) * LOG2E);
    const float lm = lh * sA + lB * sB;
    const float lf = lm + __shfl_xor(lm, 32);
    const float rin = 1.0f / lf;
    u16* cb = ctx + (tokbase + qt * 32) * 1024 + h * 64 + ln;
    #pragma unroll
    for (int r = 0; r < 16; ++r) {
      const int rm = (r & 3) + 8 * (r >> 2) + 4 * hi;
      const float sAr = __shfl(sA, rm);
      const float sBr = __shfl(sB, rm);
      const float rr  = __shfl(rin, rm);
      const float va = oa[r] * sAr + obuf[rm * 64 + ln]      * sBr;
      const float vb = ob[r] * sAr + obuf[rm * 64 + 32 + ln] * sBr;
      cb[(size_t)rm * 1024]      = f2bf(va * rr);
      cb[(size_t)rm * 1024 + 32] = f2bf(vb * rr);
    }
  }
}

// ---------------- launch ----------------

extern "C" void kernel_launch(void* const* d_in, const int* in_sizes, int n_in,
                              void* d_out, int out_size, void* d_ws, size_t ws_size,
                              hipStream_t stream) {
  const float* x  = (const float*)d_in[0];
  const float* Wq = (const float*)d_in[1];
  const float* Wk = (const float*)d_in[2];
  const float* Wv = (const float*)d_in[3];
  const float* Wo = (const float*)d_in[4];
  const float* bo = (const float*)d_in[5];
  float* out = (float*)d_out;
  char* ws = (char*)d_ws;

  // ws layout (bytes): [0,8M) xb, later reused as VT; [8M,14M) WqkvT;
  // [14M,16M) WoT; [16M,40M) QKV; [40M,48M) ctx
  u16* xb    = (u16*)(ws);
  u16* VT    = (u16*)(ws);                 // reuses xb after QKV GEMM
  u16* WqkvT = (u16*)(ws + (8u  << 20));
  u16* WoT   = (u16*)(ws + (14u << 20));
  u16* QKV   = (u16*)(ws + (16u << 20));
  u16* ctxb  = (u16*)(ws + (40u << 20));

  k_convert<<<2048, 256, 0, stream>>>(x, xb);
  k_transpose_w<<<dim3(16, 16), 256, 0, stream>>>(Wq, WqkvT);
  k_transpose_w<<<dim3(16, 16), 256, 0, stream>>>(Wk, WqkvT + (1u << 20));
  k_transpose_w<<<dim3(16, 16), 256, 0, stream>>>(Wv, WqkvT + (2u << 20));
  k_transpose_w<<<dim3(16, 16), 256, 0, stream>>>(Wo, WoT);

  // QKV = xb @ WqkvT^T : [4096][3072] bf16
  k_gemm_bt<0><<<dim3(24, 32), 256, 0, stream>>>(xb, WqkvT, QKV, nullptr, 4096, 3072, 1024);
  // V^T into global (xb region now dead)
  k_transpose_v<<<dim3(16, 64), 256, 0, stream>>>(QKV, VT);
  // causal MHA -> ctx [4096][1024] bf16
  k_attn<<<2048, 128, 0, stream>>>(QKV, VT, ctxb);
  // out = ctx @ WoT^T + bo : fp32
  k_gemm_bt<1><<<dim3(8, 32), 256, 0, stream>>>(ctxb, WoT, out, bo, 4096, 1024, 1024);
}

// Round 5
// 146.319 us; speedup vs baseline: 1.1472x; 1.1472x over previous
//
#include <hip/hip_runtime.h>

typedef unsigned short u16;
typedef unsigned int   u32;
typedef __bf16 bf16x2 __attribute__((ext_vector_type(2)));
typedef __bf16 bf16x8 __attribute__((ext_vector_type(8)));
typedef float  f32x4  __attribute__((ext_vector_type(4)));
typedef float  f32x16 __attribute__((ext_vector_type(16)));
typedef u32    u32x4  __attribute__((ext_vector_type(4)));

#define LOG2E 1.4426950408889634f

// fp32 -> bf16 round-to-nearest-even
__device__ __forceinline__ u16 f2bf(float f) {
  union { float f; u32 u; } v; v.f = f;
  u32 r = v.u + 0x7fffu + ((v.u >> 16) & 1u);
  return (u16)(r >> 16);
}

// pair-pack via __bf16 casts -> compiler selects v_cvt_pk_bf16_f32 (RNE)
__device__ __forceinline__ u32 pack2(float lo, float hi) {
  bf16x2 p = { (__bf16)lo, (__bf16)hi };
  return __builtin_bit_cast(u32, p);
}

#define GLOAD_LDS16(g, s) __builtin_amdgcn_global_load_lds( \
    (const __attribute__((address_space(1))) void*)(g),     \
    (__attribute__((address_space(3))) void*)(s), 16, 0, 0)

// ---------------- prep kernels ----------------

__global__ void k_convert(const float* __restrict__ in, u16* __restrict__ out) {
  int i = (blockIdx.x * 256 + threadIdx.x) * 8;
  float4 a = *(const float4*)(in + i);
  float4 b = *(const float4*)(in + i + 4);
  u16 o[8] = { f2bf(a.x), f2bf(a.y), f2bf(a.z), f2bf(a.w),
               f2bf(b.x), f2bf(b.y), f2bf(b.z), f2bf(b.w) };
  *(uint4*)(out + i) = *(const uint4*)o;
}

// z=0..2: W{q,k,v} -> WqkvT + z*1M elems ; z=3: Wo -> WoT.  WT[n][k] = W[k][n]
__global__ void k_transpose_w4(const float* __restrict__ Wq, const float* __restrict__ Wk,
                               const float* __restrict__ Wv, const float* __restrict__ Wo,
                               u16* __restrict__ WqkvT, u16* __restrict__ WoT) {
  const int z = blockIdx.z;
  const float* W = (z == 0) ? Wq : (z == 1) ? Wk : (z == 2) ? Wv : Wo;
  u16* WT = (z < 3) ? (WqkvT + ((size_t)z << 20)) : WoT;
  __shared__ float tile[64][65];
  const int t = threadIdx.x;
  const int n0 = blockIdx.x * 64, k0 = blockIdx.y * 64;
  const int r = t >> 4, c4 = (t & 15) * 4;
  #pragma unroll
  for (int rr = 0; rr < 64; rr += 16) {
    float4 v = *(const float4*)(W + (size_t)(k0 + r + rr) * 1024 + n0 + c4);
    tile[r + rr][c4]     = v.x; tile[r + rr][c4 + 1] = v.y;
    tile[r + rr][c4 + 2] = v.z; tile[r + rr][c4 + 3] = v.w;
  }
  __syncthreads();
  #pragma unroll
  for (int rr = 0; rr < 64; rr += 16) {
    u16 o[4] = { f2bf(tile[c4][r + rr]),     f2bf(tile[c4 + 1][r + rr]),
                 f2bf(tile[c4 + 2][r + rr]), f2bf(tile[c4 + 3][r + rr]) };
    *(ushort4*)(WT + (size_t)(n0 + r + rr) * 1024 + k0 + c4) = *(const ushort4*)o;
  }
}

// V region of QKV (cols 2048..3071) -> VT[1024][4096] bf16: VT[d][tok] = V[tok][d]
__global__ void k_transpose_v(const u16* __restrict__ qkv, u16* __restrict__ vt) {
  __shared__ u16 tile[64][72];
  const int t = threadIdx.x;
  const int c0 = blockIdx.x * 64;   // d
  const int r0 = blockIdx.y * 64;   // token
  const int rr = t >> 3;            // 0..31
  const int cc = (t & 7) * 8;       // 0..56
  #pragma unroll
  for (int j = 0; j < 2; ++j) {
    int r = rr + j * 32;
    *(uint4*)&tile[r][cc] = *(const uint4*)(qkv + (size_t)(r0 + r) * 3072 + 2048 + c0 + cc);
  }
  __syncthreads();
  #pragma unroll
  for (int j = 0; j < 2; ++j) {
    int c = rr + j * 32;
    u16 o[8];
    #pragma unroll
    for (int k = 0; k < 8; ++k) o[k] = tile[cc + k][c];
    *(uint4*)(vt + (size_t)(c0 + c) * 4096 + r0 + cc) = *(const uint4*)o;
  }
}

// ---------------- GEMM: C[M][N] = A[M][K] * BT[N][K]^T ----------------

template<int OUTF32>
__global__ __launch_bounds__(256) void k_gemm_bt(
    const u16* __restrict__ A, const u16* __restrict__ BT,
    void* __restrict__ Cv, const float* __restrict__ bias,
    int M, int N, int K) {
  __shared__ u16 lA[2][128 * 32];
  __shared__ u16 lB[2][128 * 32];
  const int t = threadIdx.x;
  const int l = t & 63, w = t >> 6;
  const int bM = blockIdx.y * 128, bN = blockIdx.x * 128;
  const int wr = w >> 1, wc = w & 1;
  const int NT = K >> 5;

  f32x4 acc[4][4] = {};

  const int fA  = w * 512 + l * 8;
  const int r0  = fA >> 5;
  const int kc0 = fA & 31;

  auto stage = [&](int buf, int kt) {
    const u16* ga = A  + (size_t)(bM + r0) * K + kt * 32 + kc0;
    const u16* gb = BT + (size_t)(bN + r0) * K + kt * 32 + kc0;
    GLOAD_LDS16(ga, &lA[buf][w * 512]);
    GLOAD_LDS16(gb, &lB[buf][w * 512]);
    GLOAD_LDS16(ga + (size_t)64 * K, &lA[buf][2048 + w * 512]);
    GLOAD_LDS16(gb + (size_t)64 * K, &lB[buf][2048 + w * 512]);
  };

  stage(0, 0);
  __syncthreads();
  int buf = 0;
  for (int kt = 0; kt < NT; ++kt) {
    if (kt + 1 < NT) stage(buf ^ 1, kt + 1);
    bf16x8 af[4], bfr[4];
    #pragma unroll
    for (int m = 0; m < 4; ++m)
      af[m] = *(const bf16x8*)&lA[buf][(wr * 64 + m * 16 + (l & 15)) * 32 + (l >> 4) * 8];
    #pragma unroll
    for (int n = 0; n < 4; ++n)
      bfr[n] = *(const bf16x8*)&lB[buf][(wc * 64 + n * 16 + (l & 15)) * 32 + (l >> 4) * 8];
    #pragma unroll
    for (int m = 0; m < 4; ++m)
      #pragma unroll
      for (int n = 0; n < 4; ++n)
        acc[m][n] = __builtin_amdgcn_mfma_f32_16x16x32_bf16(af[m], bfr[n], acc[m][n], 0, 0, 0);
    __syncthreads();
    buf ^= 1;
  }

  #pragma unroll
  for (int m = 0; m < 4; ++m) {
    #pragma unroll
    for (int n = 0; n < 4; ++n) {
      const int row = bM + wr * 64 + m * 16 + (l >> 4) * 4;
      const int col = bN + wc * 64 + n * 16 + (l & 15);
      #pragma unroll
      for (int i = 0; i < 4; ++i) {
        if (OUTF32) ((float*)Cv)[(size_t)(row + i) * N + col] = acc[m][n][i] + bias[col];
        else        ((u16*)Cv)[(size_t)(row + i) * N + col]   = f2bf(acc[m][n][i]);
      }
    }
  }
}

// ---------------- flash attention (causal, no scale) ----------------
// 1024 blocks x 256 threads (4 waves) = exactly 4 blocks/CU resident.
// Block owns (bh, qt-pair {j, 63-j}); wave w processes quarter k-ranges of
// BOTH tasks (~16.25 tiles each -> uniform waves, no tail). Per task the 4
// partial (m,l,O) states merge via 32KB LDS; all 256 threads combine+write.
// S^T via swapped mfma(K,Q) 32x32x16; C/D: col=lane&31, row=(r&3)+8(r>>2)+4hi.

__global__ __launch_bounds__(256, 2) void k_attn(
    const u16* __restrict__ qkv, const u16* __restrict__ vtg, u16* __restrict__ ctx) {
  __shared__ float obuf[4][32][64];   // [partial][q][d]
  __shared__ float mbuf[4][32];
  __shared__ float lbuf[4][32];
  __shared__ float sbuf[4][32];
  __shared__ float rbuf[32];

  const int t = threadIdx.x;
  const int l = t & 63, w = t >> 6;        // w = partial id 0..3
  const int hi = l >> 5, ln = l & 31;
  const int bidx = blockIdx.x;
  const int x = bidx & 7, g = bidx >> 3;   // XCD slot, group
  const int bh = x * 4 + (g & 3);          // 4 heads per XCD slot (L2 residency)
  const int j = g >> 2;                    // 0..31 -> tasks qt=j and qt=63-j
  const int bb = bh >> 4, h = bh & 15;
  const size_t tokbase = (size_t)bb * 2048;

  #pragma unroll 1
  for (int task = 0; task < 2; ++task) {
    const int qt = task ? (63 - j) : j;
    const int NT = qt + 1;
    const int t0 = (NT * w) >> 2;
    const int t1 = (NT * (w + 1)) >> 2;
    const int nt = t1 - t0;

    // Q B-fragments
    bf16x8 qf[4];
    {
      const u16* qq = qkv + (tokbase + qt * 32 + ln) * 3072 + h * 64 + hi * 8;
      #pragma unroll
      for (int ds = 0; ds < 4; ++ds) qf[ds] = *(const bf16x8*)(qq + ds * 16);
    }

    const u16* kp  = qkv + (tokbase + t0 * 32 + ln) * 3072 + 1024 + h * 64 + hi * 8;
    const u16* vp0 = vtg + (size_t)(h * 64 + ln) * 4096 + tokbase + t0 * 32 + hi * 8;
    const u16* vp1 = vp0 + (size_t)32 * 4096;

    f32x16 oa = {}, ob = {};
    float m = -__builtin_inff(), lh = 0.f;

    bf16x8 kA[4], kB[4];
    auto loadK = [&](bf16x8 (&kf)[4]) {
      #pragma unroll
      for (int ds = 0; ds < 4; ++ds) kf[ds] = *(const bf16x8*)(kp + ds * 16);
      kp += 32 * 3072;
    };

    auto process = [&](bf16x8 (&kf)[4], bool diag) {
      // S^T = K * Q^T
      f32x16 sc = {};
      #pragma unroll
      for (int ds = 0; ds < 4; ++ds)
        sc = __builtin_amdgcn_mfma_f32_32x32x16_bf16(kf[ds], qf[ds], sc, 0, 0, 0);

      if (diag) {
        #pragma unroll
        for (int r = 0; r < 16; ++r) {
          const int kloc = (r & 3) + 8 * (r >> 2) + 4 * hi;
          if (kloc > ln) sc[r] = -__builtin_inff();
        }
      }

      float pm = sc[0];
      #pragma unroll
      for (int r = 1; r < 16; ++r) pm = fmaxf(pm, sc[r]);
      pm = fmaxf(pm, __shfl_xor(pm, 32));

      if (!__all(pm <= m + 8.0f)) {   // defer-max (T13)
        const float mn  = fmaxf(m, pm);
        const float scl = exp2f((m - mn) * LOG2E);
        m = mn;
        lh *= scl;
        #pragma unroll
        for (int r = 0; r < 16; ++r) {
          const float sr = __shfl(scl, (r & 3) + 8 * (r >> 2) + 4 * hi);
          oa[r] *= sr; ob[r] *= sr;
        }
      }

      // V fragments (issued here: exp/pack hides the L2 latency)
      bf16x8 v00 = *(const bf16x8*)(vp0);
      bf16x8 v01 = *(const bf16x8*)(vp0 + 16);
      bf16x8 v10 = *(const bf16x8*)(vp1);
      bf16x8 v11 = *(const bf16x8*)(vp1 + 16);
      vp0 += 32; vp1 += 32;

      float ph[16];
      #pragma unroll
      for (int r = 0; r < 16; ++r) ph[r] = exp2f((sc[r] - m) * LOG2E);
      float rs = 0.f;
      #pragma unroll
      for (int r = 0; r < 16; ++r) rs += ph[r];
      lh += rs;

      u32 c0 = pack2(ph[0],  ph[1]),  c1 = pack2(ph[2],  ph[3]);
      u32 c2 = pack2(ph[4],  ph[5]),  c3 = pack2(ph[6],  ph[7]);
      u32 c4 = pack2(ph[8],  ph[9]),  c5 = pack2(ph[10], ph[11]);
      u32 c6 = pack2(ph[12], ph[13]), c7 = pack2(ph[14], ph[15]);
      const u32 s0 = __shfl_xor(c0, 32), s1 = __shfl_xor(c1, 32);
      const u32 s2 = __shfl_xor(c2, 32), s3 = __shfl_xor(c3, 32);
      const u32 s4 = __shfl_xor(c4, 32), s5 = __shfl_xor(c5, 32);
      const u32 s6 = __shfl_xor(c6, 32), s7 = __shfl_xor(c7, 32);
      const bool h0 = (hi == 0);
      u32x4 wa0 = { h0 ? c0 : s2, h0 ? c1 : s3, h0 ? s0 : c2, h0 ? s1 : c3 };
      u32x4 wa1 = { h0 ? c4 : s6, h0 ? c5 : s7, h0 ? s4 : c6, h0 ? s5 : c7 };
      bf16x8 pa0 = __builtin_bit_cast(bf16x8, wa0);
      bf16x8 pa1 = __builtin_bit_cast(bf16x8, wa1);

      oa = __builtin_amdgcn_mfma_f32_32x32x16_bf16(pa0, v00, oa, 0, 0, 0);
      oa = __builtin_amdgcn_mfma_f32_32x32x16_bf16(pa1, v01, oa, 0, 0, 0);
      ob = __builtin_amdgcn_mfma_f32_32x32x16_bf16(pa0, v10, ob, 0, 0, 0);
      ob = __builtin_amdgcn_mfma_f32_32x32x16_bf16(pa1, v11, ob, 0, 0, 0);
    };

    if (nt > 0) {
      loadK(kA);
      for (int i = 0; i < nt; i += 2) {
        const bool more1 = (i + 1 < nt);
        if (more1) loadK(kB);
        process(kA, t0 + i == qt);
        if (more1) {
          if (i + 2 < nt) loadK(kA);
          process(kB, t0 + i + 1 == qt);
        }
      }
    }

    // ---- stash this wave's partial state ----
    {
      const float lr = lh + __shfl_xor(lh, 32);
      if (hi == 0) { mbuf[w][ln] = m; lbuf[w][ln] = lr; }
      #pragma unroll
      for (int r = 0; r < 16; ++r) {
        const int rm = (r & 3) + 8 * (r >> 2) + 4 * hi;
        obuf[w][rm][ln]      = oa[r];
        obuf[w][rm][ln + 32] = ob[r];
      }
    }
    __syncthreads();

    // ---- per-row merge factors (32 threads) ----
    if (t < 32) {
      const int q = t;
      const float m0 = mbuf[0][q], m1 = mbuf[1][q], m2 = mbuf[2][q], m3 = mbuf[3][q];
      const float ms = fmaxf(fmaxf(m0, m1), fmaxf(m2, m3));
      const float s0 = exp2f((m0 - ms) * LOG2E);
      const float s1 = exp2f((m1 - ms) * LOG2E);
      const float s2 = exp2f((m2 - ms) * LOG2E);
      const float s3 = exp2f((m3 - ms) * LOG2E);
      const float ls = s0 * lbuf[0][q] + s1 * lbuf[1][q] + s2 * lbuf[2][q] + s3 * lbuf[3][q];
      sbuf[0][q] = s0; sbuf[1][q] = s1; sbuf[2][q] = s2; sbuf[3][q] = s3;
      rbuf[q] = 1.0f / ls;
    }
    __syncthreads();

    // ---- combine 4 partials + write (all 256 threads, coalesced) ----
    {
      u16* cb = ctx + (tokbase + qt * 32) * 1024 + h * 64;
      #pragma unroll
      for (int k2 = 0; k2 < 8; ++k2) {
        const int idx = t + k2 * 256;
        const int q = idx >> 6, d = idx & 63;
        const float v = sbuf[0][q] * obuf[0][q][d] + sbuf[1][q] * obuf[1][q][d]
                      + sbuf[2][q] * obuf[2][q][d] + sbuf[3][q] * obuf[3][q][d];
        cb[(size_t)q * 1024 + d] = f2bf(v * rbuf[q]);
      }
    }
    __syncthreads();   // obuf reused by next task
  }
}

// ---------------- launch ----------------

extern "C" void kernel_launch(void* const* d_in, const int* in_sizes, int n_in,
                              void* d_out, int out_size, void* d_ws, size_t ws_size,
                              hipStream_t stream) {
  const float* x  = (const float*)d_in[0];
  const float* Wq = (const float*)d_in[1];
  const float* Wk = (const float*)d_in[2];
  const float* Wv = (const float*)d_in[3];
  const float* Wo = (const float*)d_in[4];
  const float* bo = (const float*)d_in[5];
  float* out = (float*)d_out;
  char* ws = (char*)d_ws;

  // ws layout (bytes): [0,8M) xb, later reused as VT; [8M,14M) WqkvT;
  // [14M,16M) WoT; [16M,40M) QKV; [40M,48M) ctx
  u16* xb    = (u16*)(ws);
  u16* VT    = (u16*)(ws);                 // reuses xb after QKV GEMM
  u16* WqkvT = (u16*)(ws + (8u  << 20));
  u16* WoT   = (u16*)(ws + (14u << 20));
  u16* QKV   = (u16*)(ws + (16u << 20));
  u16* ctxb  = (u16*)(ws + (40u << 20));

  k_convert<<<2048, 256, 0, stream>>>(x, xb);
  k_transpose_w4<<<dim3(16, 16, 4), 256, 0, stream>>>(Wq, Wk, Wv, Wo, WqkvT, WoT);

  // QKV = xb @ WqkvT^T : [4096][3072] bf16
  k_gemm_bt<0><<<dim3(24, 32), 256, 0, stream>>>(xb, WqkvT, QKV, nullptr, 4096, 3072, 1024);
  // V^T into global (xb region now dead)
  k_transpose_v<<<dim3(16, 64), 256, 0, stream>>>(QKV, VT);
  // causal MHA -> ctx [4096][1024] bf16
  k_attn<<<1024, 256, 0, stream>>>(QKV, VT, ctxb);
  // out = ctx @ WoT^T + bo : fp32
  k_gemm_bt<1><<<dim3(8, 32), 256, 0, stream>>>(ctxb, WoT, out, bo, 4096, 1024, 1024);
}

// Round 6
// 135.965 us; speedup vs baseline: 1.2345x; 1.0762x over previous
//
#include <hip/hip_runtime.h>

typedef unsigned short u16;
typedef unsigned int   u32;
typedef __bf16 bf16x2 __attribute__((ext_vector_type(2)));
typedef __bf16 bf16x8 __attribute__((ext_vector_type(8)));
typedef float  f32x4  __attribute__((ext_vector_type(4)));
typedef float  f32x16 __attribute__((ext_vector_type(16)));
typedef u32    u32x4  __attribute__((ext_vector_type(4)));

#define LOG2E 1.4426950408889634f

// fp32 -> bf16 round-to-nearest-even
__device__ __forceinline__ u16 f2bf(float f) {
  union { float f; u32 u; } v; v.f = f;
  u32 r = v.u + 0x7fffu + ((v.u >> 16) & 1u);
  return (u16)(r >> 16);
}

// pair-pack via __bf16 casts -> compiler selects v_cvt_pk_bf16_f32 (RNE)
__device__ __forceinline__ u32 pack2(float lo, float hi) {
  bf16x2 p = { (__bf16)lo, (__bf16)hi };
  return __builtin_bit_cast(u32, p);
}

#define GLOAD_LDS16(g, s) __builtin_amdgcn_global_load_lds( \
    (const __attribute__((address_space(1))) void*)(g),     \
    (__attribute__((address_space(3))) void*)(s), 16, 0, 0)

// ---------------- prep kernels ----------------

__global__ void k_convert(const float* __restrict__ in, u16* __restrict__ out) {
  int i = (blockIdx.x * 256 + threadIdx.x) * 8;
  float4 a = *(const float4*)(in + i);
  float4 b = *(const float4*)(in + i + 4);
  u16 o[8] = { f2bf(a.x), f2bf(a.y), f2bf(a.z), f2bf(a.w),
               f2bf(b.x), f2bf(b.y), f2bf(b.z), f2bf(b.w) };
  *(uint4*)(out + i) = *(const uint4*)o;
}

// z=0..2: W{q,k,v} -> WqkvT + z*1M elems ; z=3: Wo -> WoT.  WT[n][k] = W[k][n]
__global__ void k_transpose_w4(const float* __restrict__ Wq, const float* __restrict__ Wk,
                               const float* __restrict__ Wv, const float* __restrict__ Wo,
                               u16* __restrict__ WqkvT, u16* __restrict__ WoT) {
  const int z = blockIdx.z;
  const float* W = (z == 0) ? Wq : (z == 1) ? Wk : (z == 2) ? Wv : Wo;
  u16* WT = (z < 3) ? (WqkvT + ((size_t)z << 20)) : WoT;
  __shared__ float tile[64][65];
  const int t = threadIdx.x;
  const int n0 = blockIdx.x * 64, k0 = blockIdx.y * 64;
  const int r = t >> 4, c4 = (t & 15) * 4;
  #pragma unroll
  for (int rr = 0; rr < 64; rr += 16) {
    float4 v = *(const float4*)(W + (size_t)(k0 + r + rr) * 1024 + n0 + c4);
    tile[r + rr][c4]     = v.x; tile[r + rr][c4 + 1] = v.y;
    tile[r + rr][c4 + 2] = v.z; tile[r + rr][c4 + 3] = v.w;
  }
  __syncthreads();
  #pragma unroll
  for (int rr = 0; rr < 64; rr += 16) {
    u16 o[4] = { f2bf(tile[c4][r + rr]),     f2bf(tile[c4 + 1][r + rr]),
                 f2bf(tile[c4 + 2][r + rr]), f2bf(tile[c4 + 3][r + rr]) };
    *(ushort4*)(WT + (size_t)(n0 + r + rr) * 1024 + k0 + c4) = *(const ushort4*)o;
  }
}

// ---------------- GEMM: C[M][N] = A[M][K] * BT[N][K]^T ----------------

template<int OUTF32>
__global__ __launch_bounds__(256) void k_gemm_bt(
    const u16* __restrict__ A, const u16* __restrict__ BT,
    void* __restrict__ Cv, const float* __restrict__ bias,
    int M, int N, int K) {
  __shared__ u16 lA[2][128 * 32];
  __shared__ u16 lB[2][128 * 32];
  const int t = threadIdx.x;
  const int l = t & 63, w = t >> 6;
  const int bM = blockIdx.y * 128, bN = blockIdx.x * 128;
  const int wr = w >> 1, wc = w & 1;
  const int NT = K >> 5;

  f32x4 acc[4][4] = {};

  const int fA  = w * 512 + l * 8;
  const int r0  = fA >> 5;
  const int kc0 = fA & 31;

  auto stage = [&](int buf, int kt) {
    const u16* ga = A  + (size_t)(bM + r0) * K + kt * 32 + kc0;
    const u16* gb = BT + (size_t)(bN + r0) * K + kt * 32 + kc0;
    GLOAD_LDS16(ga, &lA[buf][w * 512]);
    GLOAD_LDS16(gb, &lB[buf][w * 512]);
    GLOAD_LDS16(ga + (size_t)64 * K, &lA[buf][2048 + w * 512]);
    GLOAD_LDS16(gb + (size_t)64 * K, &lB[buf][2048 + w * 512]);
  };

  stage(0, 0);
  __syncthreads();
  int buf = 0;
  for (int kt = 0; kt < NT; ++kt) {
    if (kt + 1 < NT) stage(buf ^ 1, kt + 1);
    bf16x8 af[4], bfr[4];
    #pragma unroll
    for (int m = 0; m < 4; ++m)
      af[m] = *(const bf16x8*)&lA[buf][(wr * 64 + m * 16 + (l & 15)) * 32 + (l >> 4) * 8];
    #pragma unroll
    for (int n = 0; n < 4; ++n)
      bfr[n] = *(const bf16x8*)&lB[buf][(wc * 64 + n * 16 + (l & 15)) * 32 + (l >> 4) * 8];
    #pragma unroll
    for (int m = 0; m < 4; ++m)
      #pragma unroll
      for (int n = 0; n < 4; ++n)
        acc[m][n] = __builtin_amdgcn_mfma_f32_16x16x32_bf16(af[m], bfr[n], acc[m][n], 0, 0, 0);
    __syncthreads();
    buf ^= 1;
  }

  #pragma unroll
  for (int m = 0; m < 4; ++m) {
    #pragma unroll
    for (int n = 0; n < 4; ++n) {
      const int row = bM + wr * 64 + m * 16 + (l >> 4) * 4;
      const int col = bN + wc * 64 + n * 16 + (l & 15);
      #pragma unroll
      for (int i = 0; i < 4; ++i) {
        if (OUTF32) ((float*)Cv)[(size_t)(row + i) * N + col] = acc[m][n][i] + bias[col];
        else        ((u16*)Cv)[(size_t)(row + i) * N + col]   = f2bf(acc[m][n][i]);
      }
    }
  }
}

// ---------------- flash attention (causal, no scale) ----------------
// 512 blocks x 4 waves. Block owns causal q-quartet {g, 31-g, 32+g, 63-g}
// (uniform 130 tile-works). Single k-stream 0..63-g; each 32-token K/V tile
// staged ONCE into LDS (coalesced; V transposed in-flight via packed pairs),
// consumed by every wave with k <= qt. Double-buffered, 2 barriers/round.
// S^T via swapped mfma(K,Q) 32x32x16; C/D: col=lane&31, row=(r&3)+8(r>>2)+4hi.
// LDS pads: K [32][76] (2-way), V^T [64][36] (2-way) - free per m136.

__global__ __launch_bounds__(256, 2) void k_attn(
    const u16* __restrict__ qkv, u16* __restrict__ ctx) {
  __shared__ u16 kl[2][32][76];
  __shared__ u16 vt[2][64][36];

  const int t = threadIdx.x;
  const int l = t & 63, w = t >> 6;
  const int hi = l >> 5, ln = l & 31;
  const int bidx = blockIdx.x;
  const int x = bidx & 7;                    // XCD slot
  const int bh = x * 4 + ((bidx >> 3) & 3);  // 4 heads per XCD (KV L2-resident)
  const int g = bidx >> 5;                   // 0..15; g=0 (longest) first
  const int bb = bh >> 4, h = bh & 15;
  const size_t tokbase = (size_t)bb * 2048;

  const int qtw = (w == 0) ? g : (w == 1) ? (31 - g) : (w == 2) ? (32 + g) : (63 - g);
  const int kmax = 63 - g;

  // Q B-fragments for this wave's q-tile
  bf16x8 qf[4];
  {
    const u16* qq = qkv + (tokbase + qtw * 32 + ln) * 3072 + h * 64 + hi * 8;
    #pragma unroll
    for (int ds = 0; ds < 4; ++ds) qf[ds] = *(const bf16x8*)(qq + ds * 16);
  }

  f32x16 oa = {}, ob = {};
  float m = -__builtin_inff(), lh = 0.f;

  // staging roles: t<128 stages V (transpose in-flight), t>=128 stages K
  uint4 sr0, sr1;
  const int vp_ = t & 15, vdg = t >> 4;            // t<128: token-pair, d-group
  const int kc_ = (t - 128) * 2;
  const int kr_ = kc_ >> 3, kcc = kc_ & 7;         // t>=128: row, col-chunk

  auto loads = [&](int kt) {
    if (t < 128) {
      const u16* vp = qkv + (tokbase + kt * 32 + 2 * vp_) * 3072 + 2048 + h * 64 + vdg * 8;
      sr0 = *(const uint4*)vp;
      sr1 = *(const uint4*)(vp + 3072);
    } else {
      const u16* kp = qkv + (tokbase + kt * 32 + kr_) * 3072 + 1024 + h * 64 + kcc * 8;
      sr0 = *(const uint4*)kp;
      sr1 = *(const uint4*)(kp + 8);
    }
  };
  auto writes = [&](int buf) {
    if (t < 128) {
      const u16* a = (const u16*)&sr0;
      const u16* b = (const u16*)&sr1;
      #pragma unroll
      for (int i = 0; i < 8; ++i)
        *(u32*)&vt[buf][vdg * 8 + i][2 * vp_] = (u32)a[i] | ((u32)b[i] << 16);
    } else {
      *(uint4*)&kl[buf][kr_][kcc * 8]     = sr0;
      *(uint4*)&kl[buf][kr_][kcc * 8 + 8] = sr1;
    }
  };

  auto compute = [&](int buf, bool diag) {
    bf16x8 kf[4];
    #pragma unroll
    for (int ds = 0; ds < 4; ++ds)
      kf[ds] = *(const bf16x8*)&kl[buf][ln][ds * 16 + hi * 8];

    // S^T = K * Q^T
    f32x16 sc = {};
    #pragma unroll
    for (int ds = 0; ds < 4; ++ds)
      sc = __builtin_amdgcn_mfma_f32_32x32x16_bf16(kf[ds], qf[ds], sc, 0, 0, 0);

    if (diag) {
      #pragma unroll
      for (int r = 0; r < 16; ++r) {
        const int kloc = (r & 3) + 8 * (r >> 2) + 4 * hi;
        if (kloc > ln) sc[r] = -__builtin_inff();
      }
    }

    float pm = sc[0];
    #pragma unroll
    for (int r = 1; r < 16; ++r) pm = fmaxf(pm, sc[r]);
    pm = fmaxf(pm, __shfl_xor(pm, 32));

    if (!__all(pm <= m + 8.0f)) {   // defer-max (T13)
      const float mn  = fmaxf(m, pm);
      const float scl = exp2f((m - mn) * LOG2E);
      m = mn;
      lh *= scl;
      #pragma unroll
      for (int r = 0; r < 16; ++r) {
        const float sr = __shfl(scl, (r & 3) + 8 * (r >> 2) + 4 * hi);
        oa[r] *= sr; ob[r] *= sr;
      }
    }

    bf16x8 v00 = *(const bf16x8*)&vt[buf][ln][hi * 8];
    bf16x8 v01 = *(const bf16x8*)&vt[buf][ln][16 + hi * 8];
    bf16x8 v10 = *(const bf16x8*)&vt[buf][ln + 32][hi * 8];
    bf16x8 v11 = *(const bf16x8*)&vt[buf][ln + 32][16 + hi * 8];

    float ph[16];
    #pragma unroll
    for (int r = 0; r < 16; ++r) ph[r] = exp2f((sc[r] - m) * LOG2E);
    float rs = 0.f;
    #pragma unroll
    for (int r = 0; r < 16; ++r) rs += ph[r];
    lh += rs;

    u32 c0 = pack2(ph[0],  ph[1]),  c1 = pack2(ph[2],  ph[3]);
    u32 c2 = pack2(ph[4],  ph[5]),  c3 = pack2(ph[6],  ph[7]);
    u32 c4 = pack2(ph[8],  ph[9]),  c5 = pack2(ph[10], ph[11]);
    u32 c6 = pack2(ph[12], ph[13]), c7 = pack2(ph[14], ph[15]);
    const u32 s0 = __shfl_xor(c0, 32), s1 = __shfl_xor(c1, 32);
    const u32 s2 = __shfl_xor(c2, 32), s3 = __shfl_xor(c3, 32);
    const u32 s4 = __shfl_xor(c4, 32), s5 = __shfl_xor(c5, 32);
    const u32 s6 = __shfl_xor(c6, 32), s7 = __shfl_xor(c7, 32);
    const bool h0 = (hi == 0);
    u32x4 wa0 = { h0 ? c0 : s2, h0 ? c1 : s3, h0 ? s0 : c2, h0 ? s1 : c3 };
    u32x4 wa1 = { h0 ? c4 : s6, h0 ? c5 : s7, h0 ? s4 : c6, h0 ? s5 : c7 };
    bf16x8 pa0 = __builtin_bit_cast(bf16x8, wa0);
    bf16x8 pa1 = __builtin_bit_cast(bf16x8, wa1);

    oa = __builtin_amdgcn_mfma_f32_32x32x16_bf16(pa0, v00, oa, 0, 0, 0);
    oa = __builtin_amdgcn_mfma_f32_32x32x16_bf16(pa1, v01, oa, 0, 0, 0);
    ob = __builtin_amdgcn_mfma_f32_32x32x16_bf16(pa0, v10, ob, 0, 0, 0);
    ob = __builtin_amdgcn_mfma_f32_32x32x16_bf16(pa1, v11, ob, 0, 0, 0);
  };

  // prologue: stage tile 0
  loads(0);
  writes(0);
  __syncthreads();

  int buf = 0;
  for (int kt = 0; kt <= kmax; ++kt) {
    const bool pre = (kt < kmax);
    if (pre) loads(kt + 1);              // issue early (T14): HBM/L2 latency
    if (kt <= qtw) compute(buf, kt == qtw);  // hides under compute
    __syncthreads();
    if (pre) {
      writes(buf ^ 1);
      __syncthreads();
    }
    buf ^= 1;
  }

  // epilogue: O / lsum, write own q-tile
  const float lf  = lh + __shfl_xor(lh, 32);
  const float rin = 1.0f / lf;
  u16* cb = ctx + (tokbase + qtw * 32) * 1024 + h * 64 + ln;
  #pragma unroll
  for (int r = 0; r < 16; ++r) {
    const int rm = (r & 3) + 8 * (r >> 2) + 4 * hi;
    const float rr = __shfl(rin, rm);
    cb[(size_t)rm * 1024]      = f2bf(oa[r] * rr);
    cb[(size_t)rm * 1024 + 32] = f2bf(ob[r] * rr);
  }
}

// ---------------- launch ----------------

extern "C" void kernel_launch(void* const* d_in, const int* in_sizes, int n_in,
                              void* d_out, int out_size, void* d_ws, size_t ws_size,
                              hipStream_t stream) {
  const float* x  = (const float*)d_in[0];
  const float* Wq = (const float*)d_in[1];
  const float* Wk = (const float*)d_in[2];
  const float* Wv = (const float*)d_in[3];
  const float* Wo = (const float*)d_in[4];
  const float* bo = (const float*)d_in[5];
  float* out = (float*)d_out;
  char* ws = (char*)d_ws;

  // ws layout (bytes): [0,8M) xb; [8M,14M) WqkvT; [14M,16M) WoT;
  // [16M,40M) QKV; [40M,48M) ctx
  u16* xb    = (u16*)(ws);
  u16* WqkvT = (u16*)(ws + (8u  << 20));
  u16* WoT   = (u16*)(ws + (14u << 20));
  u16* QKV   = (u16*)(ws + (16u << 20));
  u16* ctxb  = (u16*)(ws + (40u << 20));

  k_convert<<<2048, 256, 0, stream>>>(x, xb);
  k_transpose_w4<<<dim3(16, 16, 4), 256, 0, stream>>>(Wq, Wk, Wv, Wo, WqkvT, WoT);

  // QKV = xb @ WqkvT^T : [4096][3072] bf16
  k_gemm_bt<0><<<dim3(24, 32), 256, 0, stream>>>(xb, WqkvT, QKV, nullptr, 4096, 3072, 1024);
  // causal MHA -> ctx [4096][1024] bf16 (K/V staged from QKV directly)
  k_attn<<<512, 256, 0, stream>>>(QKV, ctxb);
  // out = ctx @ WoT^T + bo : fp32
  k_gemm_bt<1><<<dim3(8, 32), 256, 0, stream>>>(ctxb, WoT, out, bo, 4096, 1024, 1024);
}

// Round 7
// 124.803 us; speedup vs baseline: 1.3449x; 1.0894x over previous
//
#include <hip/hip_runtime.h>

typedef unsigned short u16;
typedef unsigned int   u32;
typedef __bf16 bf16x2 __attribute__((ext_vector_type(2)));
typedef __bf16 bf16x8 __attribute__((ext_vector_type(8)));
typedef float  f32x4  __attribute__((ext_vector_type(4)));
typedef float  f32x16 __attribute__((ext_vector_type(16)));
typedef u32    u32x4  __attribute__((ext_vector_type(4)));

#define LOG2E 1.4426950408889634f

// fp32 -> bf16 round-to-nearest-even
__device__ __forceinline__ u16 f2bf(float f) {
  union { float f; u32 u; } v; v.f = f;
  u32 r = v.u + 0x7fffu + ((v.u >> 16) & 1u);
  return (u16)(r >> 16);
}

// pair-pack via __bf16 casts -> compiler selects v_cvt_pk_bf16_f32 (RNE)
__device__ __forceinline__ u32 pack2(float lo, float hi) {
  bf16x2 p = { (__bf16)lo, (__bf16)hi };
  return __builtin_bit_cast(u32, p);
}

#define GLOAD_LDS16(g, s) __builtin_amdgcn_global_load_lds( \
    (const __attribute__((address_space(1))) void*)(g),     \
    (__attribute__((address_space(3))) void*)(s), 16, 0, 0)

// ---------------- prep kernels ----------------

__global__ void k_convert(const float* __restrict__ in, u16* __restrict__ out) {
  int i = (blockIdx.x * 256 + threadIdx.x) * 8;
  float4 a = *(const float4*)(in + i);
  float4 b = *(const float4*)(in + i + 4);
  u16 o[8] = { f2bf(a.x), f2bf(a.y), f2bf(a.z), f2bf(a.w),
               f2bf(b.x), f2bf(b.y), f2bf(b.z), f2bf(b.w) };
  *(uint4*)(out + i) = *(const uint4*)o;
}

// z=0..2: W{q,k,v} -> WqkvT + z*1M elems ; z=3: Wo -> WoT.  WT[n][k] = W[k][n]
__global__ void k_transpose_w4(const float* __restrict__ Wq, const float* __restrict__ Wk,
                               const float* __restrict__ Wv, const float* __restrict__ Wo,
                               u16* __restrict__ WqkvT, u16* __restrict__ WoT) {
  const int z = blockIdx.z;
  const float* W = (z == 0) ? Wq : (z == 1) ? Wk : (z == 2) ? Wv : Wo;
  u16* WT = (z < 3) ? (WqkvT + ((size_t)z << 20)) : WoT;
  __shared__ float tile[64][65];
  const int t = threadIdx.x;
  const int n0 = blockIdx.x * 64, k0 = blockIdx.y * 64;
  const int r = t >> 4, c4 = (t & 15) * 4;
  #pragma unroll
  for (int rr = 0; rr < 64; rr += 16) {
    float4 v = *(const float4*)(W + (size_t)(k0 + r + rr) * 1024 + n0 + c4);
    tile[r + rr][c4]     = v.x; tile[r + rr][c4 + 1] = v.y;
    tile[r + rr][c4 + 2] = v.z; tile[r + rr][c4 + 3] = v.w;
  }
  __syncthreads();
  #pragma unroll
  for (int rr = 0; rr < 64; rr += 16) {
    u16 o[4] = { f2bf(tile[c4][r + rr]),     f2bf(tile[c4 + 1][r + rr]),
                 f2bf(tile[c4 + 2][r + rr]), f2bf(tile[c4 + 3][r + rr]) };
    *(ushort4*)(WT + (size_t)(n0 + r + rr) * 1024 + k0 + c4) = *(const ushort4*)o;
  }
}

// ---------------- GEMM: C[M][N] = A[M][K] * BT[N][K]^T ----------------
// MODE 0: C bf16 row-major. MODE 1: C f32 + bias. MODE 2: QKV split tile-major:
//   Q/K: plane[bh][tile][tok32][d64]; V: plane[bh][tile][d64][tok32].
//   Cv points at Qt; Kt at +4M elems; Vt at +8M elems.

template<int MODE>
__global__ __launch_bounds__(256) void k_gemm_bt(
    const u16* __restrict__ A, const u16* __restrict__ BT,
    void* __restrict__ Cv, const float* __restrict__ bias,
    int M, int N, int K) {
  __shared__ u16 lA[2][128 * 32];
  __shared__ u16 lB[2][128 * 32];
  const int t = threadIdx.x;
  const int l = t & 63, w = t >> 6;
  const int bM = blockIdx.y * 128, bN = blockIdx.x * 128;
  const int wr = w >> 1, wc = w & 1;
  const int NT = K >> 5;

  f32x4 acc[4][4] = {};

  const int fA  = w * 512 + l * 8;
  const int r0  = fA >> 5;
  const int kc0 = fA & 31;

  auto stage = [&](int buf, int kt) {
    const u16* ga = A  + (size_t)(bM + r0) * K + kt * 32 + kc0;
    const u16* gb = BT + (size_t)(bN + r0) * K + kt * 32 + kc0;
    GLOAD_LDS16(ga, &lA[buf][w * 512]);
    GLOAD_LDS16(gb, &lB[buf][w * 512]);
    GLOAD_LDS16(ga + (size_t)64 * K, &lA[buf][2048 + w * 512]);
    GLOAD_LDS16(gb + (size_t)64 * K, &lB[buf][2048 + w * 512]);
  };

  stage(0, 0);
  __syncthreads();
  int buf = 0;
  for (int kt = 0; kt < NT; ++kt) {
    if (kt + 1 < NT) stage(buf ^ 1, kt + 1);
    bf16x8 af[4], bfr[4];
    #pragma unroll
    for (int m = 0; m < 4; ++m)
      af[m] = *(const bf16x8*)&lA[buf][(wr * 64 + m * 16 + (l & 15)) * 32 + (l >> 4) * 8];
    #pragma unroll
    for (int n = 0; n < 4; ++n)
      bfr[n] = *(const bf16x8*)&lB[buf][(wc * 64 + n * 16 + (l & 15)) * 32 + (l >> 4) * 8];
    #pragma unroll
    for (int m = 0; m < 4; ++m)
      #pragma unroll
      for (int n = 0; n < 4; ++n)
        acc[m][n] = __builtin_amdgcn_mfma_f32_16x16x32_bf16(af[m], bfr[n], acc[m][n], 0, 0, 0);
    __syncthreads();
    buf ^= 1;
  }

  #pragma unroll
  for (int m = 0; m < 4; ++m) {
    #pragma unroll
    for (int n = 0; n < 4; ++n) {
      const int row = bM + wr * 64 + m * 16 + (l >> 4) * 4;
      const int col = bN + wc * 64 + n * 16 + (l & 15);
      if (MODE == 1) {
        #pragma unroll
        for (int i = 0; i < 4; ++i)
          ((float*)Cv)[(size_t)(row + i) * N + col] = acc[m][n][i] + bias[col];
      } else if (MODE == 0) {
        #pragma unroll
        for (int i = 0; i < 4; ++i)
          ((u16*)Cv)[(size_t)(row + i) * N + col] = f2bf(acc[m][n][i]);
      } else {
        // tile-major QKV epilogue (4 rows share bh/tile: row 4-aligned)
        const int which = col >> 10;            // 0=Q 1=K 2=V
        const int h  = (col >> 6) & 15;
        const int d  = col & 63;
        const int b  = row >> 11;
        const int bh = b * 16 + h;
        const int tile = (row & 2047) >> 5;
        const int tk = row & 31;
        u16* base = (u16*)Cv + (size_t)which * 4194304 + (size_t)bh * 131072 + tile * 2048;
        if (which == 2) {
          u16 o[4] = { f2bf(acc[m][n][0]), f2bf(acc[m][n][1]),
                       f2bf(acc[m][n][2]), f2bf(acc[m][n][3]) };
          *(ushort4*)(base + d * 32 + tk) = *(const ushort4*)o;   // [d][tok]
        } else {
          #pragma unroll
          for (int i = 0; i < 4; ++i)
            base[(tk + i) * 64 + d] = f2bf(acc[m][n][i]);          // [tok][d]
        }
      }
    }
  }
}

// ---------------- flash attention (causal, no scale) ----------------
// 1024 blocks x 4 waves = 4 blocks/CU. Block owns (bh, pair {j, 63-j}) --
// exactly 65 tile-works for EVERY block. The 4 waves split the concatenated
// work [chain qt=63-j: kt 0..63-j] ++ [chain qt=j: kt 0..j] into ~16.25-tile
// spans, each keeping private (m,l,O); partials merge once at block end via
// LDS (5 barriers total, none per tile). Direct tile-major loads (no staging):
// a wave's fragment loads collectively consume whole 4KB tiles through L1.
// S^T via swapped mfma(K,Q) 32x32x16; C/D: col=lane&31, row=(r&3)+8(r>>2)+4hi.

__global__ __launch_bounds__(256, 4) void k_attn(
    const u16* __restrict__ qt_, const u16* __restrict__ kt_,
    const u16* __restrict__ vt_, u16* __restrict__ ctx) {
  __shared__ float obuf[4][32][64];   // [slot][q][d]
  __shared__ float mbuf[4][32];
  __shared__ float lbuf[4][32];
  __shared__ float sbuf[4][32];
  __shared__ float rbuf[32];

  const int t = threadIdx.x;
  const int l = t & 63, w = t >> 6;
  const int hi = l >> 5, ln = l & 31;
  const int bidx = blockIdx.x;
  const int x = bidx & 7;                    // XCD slot
  const int bh = x * 4 + ((bidx >> 3) & 3);  // 4 heads per XCD (KV L2-resident)
  const int j = bidx >> 5;                   // 0..31
  const int bb = bh >> 4, h = bh & 15;
  const size_t tokbase = (size_t)bb * 2048;
  const size_t hplane = (size_t)bh * 131072;

  const int B  = 64 - j;                     // boundary in concat space
  const int s0 = (65 * w) >> 2, s1 = (65 * (w + 1)) >> 2;

  f32x16 oa = {}, ob = {};
  float m = -__builtin_inff(), lh = 0.f;

  auto process = [&](const u16* kb, const u16* vb, const bf16x8 (&qf)[4], bool diag) {
    bf16x8 kf[4];
    #pragma unroll
    for (int ds = 0; ds < 4; ++ds)
      kf[ds] = *(const bf16x8*)(kb + ln * 64 + ds * 16 + hi * 8);

    f32x16 sc = {};
    #pragma unroll
    for (int ds = 0; ds < 4; ++ds)
      sc = __builtin_amdgcn_mfma_f32_32x32x16_bf16(kf[ds], qf[ds], sc, 0, 0, 0);

    // V fragments issued early: softmax below hides the L1/L2 latency
    bf16x8 v00 = *(const bf16x8*)(vb + ln * 32 + hi * 8);
    bf16x8 v01 = *(const bf16x8*)(vb + ln * 32 + 16 + hi * 8);
    bf16x8 v10 = *(const bf16x8*)(vb + (ln + 32) * 32 + hi * 8);
    bf16x8 v11 = *(const bf16x8*)(vb + (ln + 32) * 32 + 16 + hi * 8);

    if (diag) {
      #pragma unroll
      for (int r = 0; r < 16; ++r) {
        const int kloc = (r & 3) + 8 * (r >> 2) + 4 * hi;
        if (kloc > ln) sc[r] = -__builtin_inff();
      }
    }

    float pm = sc[0];
    #pragma unroll
    for (int r = 1; r < 16; ++r) pm = fmaxf(pm, sc[r]);
    pm = fmaxf(pm, __shfl_xor(pm, 32));

    if (!__all(pm <= m + 8.0f)) {   // defer-max (T13)
      const float mn  = fmaxf(m, pm);
      const float scl = exp2f((m - mn) * LOG2E);
      m = mn;
      lh *= scl;
      #pragma unroll
      for (int r = 0; r < 16; ++r) {
        const float sr = __shfl(scl, (r & 3) + 8 * (r >> 2) + 4 * hi);
        oa[r] *= sr; ob[r] *= sr;
      }
    }

    float ph[16];
    #pragma unroll
    for (int r = 0; r < 16; ++r) ph[r] = exp2f((sc[r] - m) * LOG2E);
    float rs = 0.f;
    #pragma unroll
    for (int r = 0; r < 16; ++r) rs += ph[r];
    lh += rs;

    u32 c0 = pack2(ph[0],  ph[1]),  c1 = pack2(ph[2],  ph[3]);
    u32 c2 = pack2(ph[4],  ph[5]),  c3 = pack2(ph[6],  ph[7]);
    u32 c4 = pack2(ph[8],  ph[9]),  c5 = pack2(ph[10], ph[11]);
    u32 c6 = pack2(ph[12], ph[13]), c7 = pack2(ph[14], ph[15]);
    const u32 q0 = __shfl_xor(c0, 32), q1 = __shfl_xor(c1, 32);
    const u32 q2 = __shfl_xor(c2, 32), q3 = __shfl_xor(c3, 32);
    const u32 q4 = __shfl_xor(c4, 32), q5 = __shfl_xor(c5, 32);
    const u32 q6 = __shfl_xor(c6, 32), q7 = __shfl_xor(c7, 32);
    const bool h0 = (hi == 0);
    u32x4 wa0 = { h0 ? c0 : q2, h0 ? c1 : q3, h0 ? q0 : c2, h0 ? q1 : c3 };
    u32x4 wa1 = { h0 ? c4 : q6, h0 ? c5 : q7, h0 ? q4 : c6, h0 ? q5 : c7 };
    bf16x8 pa0 = __builtin_bit_cast(bf16x8, wa0);
    bf16x8 pa1 = __builtin_bit_cast(bf16x8, wa1);

    oa = __builtin_amdgcn_mfma_f32_32x32x16_bf16(pa0, v00, oa, 0, 0, 0);
    oa = __builtin_amdgcn_mfma_f32_32x32x16_bf16(pa1, v01, oa, 0, 0, 0);
    ob = __builtin_amdgcn_mfma_f32_32x32x16_bf16(pa0, v10, ob, 0, 0, 0);
    ob = __builtin_amdgcn_mfma_f32_32x32x16_bf16(pa1, v11, ob, 0, 0, 0);
  };

  auto stash = [&](int slot) {
    const float lr = lh + __shfl_xor(lh, 32);
    if (hi == 0) { mbuf[slot][ln] = m; lbuf[slot][ln] = lr; }
    #pragma unroll
    for (int r = 0; r < 16; ++r) {
      const int rm = (r & 3) + 8 * (r >> 2) + 4 * hi;
      obuf[slot][rm][ln]      = oa[r];
      obuf[slot][rm][ln + 32] = ob[r];
    }
  };

  auto runChain = [&](int qt, int k0, int k1) {
    if (k0 >= k1) return;
    bf16x8 qf[4];
    const u16* qq = qt_ + hplane + qt * 2048 + ln * 64 + hi * 8;
    #pragma unroll
    for (int ds = 0; ds < 4; ++ds) qf[ds] = *(const bf16x8*)(qq + ds * 16);
    const u16* kb = kt_ + hplane + k0 * 2048;
    const u16* vb = vt_ + hplane + k0 * 2048;
    for (int kt = k0; kt < k1; ++kt) {
      process(kb, vb, qf, kt == qt);
      kb += 2048; vb += 2048;
    }
  };

  auto mergeWrite = [&](int qt) {
    if (t < 32) {
      const int q = t;
      const float m0 = mbuf[0][q], m1 = mbuf[1][q], m2 = mbuf[2][q], m3 = mbuf[3][q];
      const float ms = fmaxf(fmaxf(m0, m1), fmaxf(m2, m3));
      const float f0 = exp2f((m0 - ms) * LOG2E);
      const float f1 = exp2f((m1 - ms) * LOG2E);
      const float f2 = exp2f((m2 - ms) * LOG2E);
      const float f3 = exp2f((m3 - ms) * LOG2E);
      const float ls = f0 * lbuf[0][q] + f1 * lbuf[1][q] + f2 * lbuf[2][q] + f3 * lbuf[3][q];
      sbuf[0][q] = f0; sbuf[1][q] = f1; sbuf[2][q] = f2; sbuf[3][q] = f3;
      rbuf[q] = 1.0f / ls;
    }
    __syncthreads();
    u16* cb = ctx + (tokbase + qt * 32) * 1024 + h * 64;
    #pragma unroll
    for (int k2 = 0; k2 < 8; ++k2) {
      const int idx = t + k2 * 256;
      const int q = idx >> 6, d = idx & 63;
      const float v = sbuf[0][q] * obuf[0][q][d] + sbuf[1][q] * obuf[1][q][d]
                    + sbuf[2][q] * obuf[2][q][d] + sbuf[3][q] * obuf[3][q][d];
      cb[(size_t)q * 1024 + d] = f2bf(v * rbuf[q]);
    }
  };

  // phase 0: chain qt=63-j, tiles [s0, min(s1,B))
  runChain(63 - j, s0, (s1 < B) ? s1 : B);
  stash(w);
  // reset, phase 1: chain qt=j, tiles [max(s0,B)-B, s1-B)
  oa = f32x16{}; ob = f32x16{}; m = -__builtin_inff(); lh = 0.f;
  runChain(j, ((s0 > B) ? s0 : B) - B, s1 - B);

  __syncthreads();
  mergeWrite(63 - j);          // merge chain-0 partials, write q-tile 63-j
  __syncthreads();             // slots free to overwrite
  stash(w);                    // chain-1 partials
  __syncthreads();
  mergeWrite(j);
}

// ---------------- launch ----------------

extern "C" void kernel_launch(void* const* d_in, const int* in_sizes, int n_in,
                              void* d_out, int out_size, void* d_ws, size_t ws_size,
                              hipStream_t stream) {
  const float* x  = (const float*)d_in[0];
  const float* Wq = (const float*)d_in[1];
  const float* Wk = (const float*)d_in[2];
  const float* Wv = (const float*)d_in[3];
  const float* Wo = (const float*)d_in[4];
  const float* bo = (const float*)d_in[5];
  float* out = (float*)d_out;
  char* ws = (char*)d_ws;

  // ws layout (bytes): [0,8M) xb; [8M,14M) WqkvT; [14M,16M) WoT;
  // [16M,40M) Qt/Kt/Vt tile-major (8MB each); [40M,48M) ctx
  u16* xb    = (u16*)(ws);
  u16* WqkvT = (u16*)(ws + (8u  << 20));
  u16* WoT   = (u16*)(ws + (14u << 20));
  u16* Qt    = (u16*)(ws + (16u << 20));
  u16* Kt    = (u16*)(ws + (24u << 20));
  u16* Vt    = (u16*)(ws + (32u << 20));
  u16* ctxb  = (u16*)(ws + (40u << 20));

  k_convert<<<2048, 256, 0, stream>>>(x, xb);
  k_transpose_w4<<<dim3(16, 16, 4), 256, 0, stream>>>(Wq, Wk, Wv, Wo, WqkvT, WoT);

  // QKV = xb @ WqkvT^T, written straight into tile-major Qt/Kt/Vt
  k_gemm_bt<2><<<dim3(24, 32), 256, 0, stream>>>(xb, WqkvT, Qt, nullptr, 4096, 3072, 1024);
  // causal MHA -> ctx [4096][1024] bf16
  k_attn<<<1024, 256, 0, stream>>>(Qt, Kt, Vt, ctxb);
  // out = ctx @ WoT^T + bo : fp32
  k_gemm_bt<1><<<dim3(8, 32), 256, 0, stream>>>(ctxb, WoT, out, bo, 4096, 1024, 1024);
}